// Round 8
// baseline (322.648 us; speedup 1.0000x reference)
//
#include <hip/hip_runtime.h>
#include <math.h>

#define B_TOT 4096
#define TE 168
#define TD 24
#define NWG 256          // 16 batches per WG; 768 threads -> 3 waves/SIMD
#define HSTR 72          // padded f16 row stride (144 B, 16B-aligned)

typedef _Float16 f16;
typedef __attribute__((ext_vector_type(8))) _Float16 f16x8;
typedef __attribute__((ext_vector_type(4))) float f32x4;

// Activation pre-scaling folded into weights/biases:
//   i,f,o: w *= -log2(e)  -> E = exp2(y) = e^{-x}; sigmoid = 1/(1+E)
//   g:     w *= 2*log2(e) -> E = e^{2x};  tanh = (E-1)/(E+1)
#define SCL_S (-1.4426950408889634f)
#define SCL_G (2.885390081777927f)

// ---------------------------------------------------------------------------
// Pack weights into MFMA B-fragment order, f16, pre-scaled per gate:
//   pk[w][l][q][c][lane][j] = scale_q * Wcomb_l[q*64+w*16+(lane&15)][c*32+(lane>>4)*8+j]
//   l=0 (K=96):  k<8 -> Wih0; 8..31 -> 0; 32..95 -> Whh0[k-32]  (c=3 all zero)
//   l=1 (K=128): k<64 -> Wih1 (input h0); else Whh1[k-64] (recurrent h1)
//   l=2 (K=128): k<64 -> Wih2 (input h1); else Whh2[k-64] (recurrent h2)
// ---------------------------------------------------------------------------
__global__ __launch_bounds__(256) void pack_kernel(
    const float* __restrict__ Wih0, const float* __restrict__ Whh0,
    const float* __restrict__ Wih1, const float* __restrict__ Whh1,
    const float* __restrict__ Wih2, const float* __restrict__ Whh2,
    f16* __restrict__ pk)
{
    int idx = blockIdx.x * 256 + threadIdx.x;   // 0 .. 98303
    int j = idx & 7;
    int t = idx >> 3;
    int ln = t & 63; t >>= 6;
    int c  = t & 3;  t >>= 2;
    int q  = t & 3;  t >>= 2;
    int l  = t % 3;
    int w  = t / 3;
    int row = q * 64 + w * 16 + (ln & 15);
    int k   = c * 32 + ((ln >> 4) << 3) + j;
    float val = 0.f;
    if (l == 0) {
        if (k < 8)                 val = Wih0[row * 8 + k];
        else if (k >= 32 && k < 96) val = Whh0[row * 64 + (k - 32)];
    } else if (l == 1) {
        val = (k < 64) ? Wih1[row * 64 + k] : Whh1[row * 64 + (k - 64)];
    } else {
        val = (k < 64) ? Wih2[row * 64 + k] : Whh2[row * 64 + (k - 64)];
    }
    const float sc = (q == 2) ? SCL_G : SCL_S;
    pk[idx] = (f16)(val * sc);
}

// softplus via 2 HW trans ops (no libm log1pf):
//   softplus(x) = max(x,0) + ln2 * log2(1 + 2^(-|x|*log2e))
__device__ __forceinline__ float softplusf(float x) {
    float t = fabsf(x) * 1.4426950408889634f;
    float E = __builtin_amdgcn_exp2f(-t);
    float L = __builtin_amdgcn_logf(1.f + E);      // log2
    return fmaxf(x, 0.f) + 0.6931471805599453f * L;
}

// ---------------------------------------------------------------------------
// 256 WGs x 768 threads (12 waves); WG owns 16 batches (M=16 tile dense).
// One LAYER per wave role: role = tid>>8 -> 0:L0, 1:L1, 2:L2; within a role,
// wave wv owns hid block wv*16..+16. Encoder layer-pipelined: round r
// computes L0(r), L1(r-1), L2(r-2); ONE RBAR per round.
//
// R15 = R13 champion + breadth-first CELL (explicit interleave of the 4
// per-row trans chains: 16 exp2 -> VALU -> 4 rcp -> VALU -> 4 exp2 ->
// 4 rcp -> writes; shortens the CELL dependency region from up to 4 serial
// ~100cy chains to ~1 chain + issue). All transient, nothing live across
// barriers in divergent code (R11/R14 spill lesson).
// __launch_bounds__(768,2): VGPR cap 128 (cap = 256/arg2, R12 lesson);
// occupancy is WG-bound at 1 WG/CU regardless.
// ---------------------------------------------------------------------------
__global__ __launch_bounds__(768, 2) void lstm_kernel(
    const float* __restrict__ enc_x, const float* __restrict__ enc_z,
    const float* __restrict__ dec_x, const float* __restrict__ v,
    const float* __restrict__ eps,   const f16* __restrict__ pk,
    const float* __restrict__ b0, const float* __restrict__ b1,
    const float* __restrict__ b2,
    const float* __restrict__ w_m, const float* __restrict__ b_m,
    const float* __restrict__ w_a, const float* __restrict__ b_a,
    float* __restrict__ out)
{
    const int tid  = threadIdx.x;
    const int lane = tid & 63;
    const int wv   = (tid >> 6) & 3;    // hid block within role
    const int role = tid >> 8;          // 0:L0, 1:L1, 2:L2
    const int bg   = blockIdx.x * 16;
    const int m16  = lane & 15;
    const int quad = lane >> 4;

    __shared__ f16 hbuf[2][3][16][HSTR];   // [parity][layer][batch][hid]

    // ---- zero LDS ----
    {
        uint* hz = (uint*)&hbuf[0][0][0][0];
        const int HW = 2 * 3 * 16 * HSTR / 2;   // 3456 words
        for (int i = tid; i < HW; i += 768) hz[i] = 0u;
    }

    // ---- weight fragments: this wave's layer only; register-resident ----
    f16x8 wgt[4][4];                    // [chunk][gate]
#define PKOFF(l, q, c) ((((((size_t)wv * 3 + (l)) * 4 + (q)) * 4 + (c)) * 64 + lane) * 8)
    {
        const f16* pkr = pk + PKOFF(role, 0, 0);
#pragma unroll
        for (int q = 0; q < 4; ++q)
#pragma unroll
            for (int c = 0; c < 4; ++c)
                wgt[c][q] = *(const f16x8*)(pkr + (q * 4 + c) * 64 * 8);
    }
#undef PKOFF

    const int hid_self = wv * 16 + m16;
    // bias splats (pre-scaled) for this wave's layer; MFMA C operand
    f32x4 bsp[4];
    {
        const float* bp = (role == 0) ? b0 : (role == 1) ? b1 : b2;
#pragma unroll
        for (int q = 0; q < 4; ++q) {
            const float sc = (q == 2) ? SCL_G : SCL_S;
            float bv = bp[q * 64 + hid_self] * sc;
            bsp[q] = (f32x4){bv, bv, bv, bv};
        }
    }

    f16* hb = &hbuf[0][0][0][0];
    const int aoff = m16 * HSTR + quad * 8;
    float cst[4] = {};                  // cell state for this wave's layer

// Raw barrier: drain only LDS ops (lgkmcnt); globals stay in flight.
#define RBAR                                                                  \
    {                                                                         \
        asm volatile("s_waitcnt lgkmcnt(0)" ::: "memory");                    \
        __builtin_amdgcn_s_barrier();                                         \
        asm volatile("" ::: "memory");                                        \
    }

#define PRIO_UP __builtin_amdgcn_s_setprio(1)
#define PRIO_DN __builtin_amdgcn_s_setprio(0)

#define HBASE(pp, l) (hb + ((pp) * 3 + (l)) * (16 * HSTR))
#define MFMA16(af, bf, cf) __builtin_amdgcn_mfma_f32_16x16x32_f16(af, bf, cf, 0, 0, 0)

#define MM_R(P, areg, wi)                                                     \
    {                                                                         \
        P##0 = MFMA16(areg, wgt[wi][0], bsp[0]);                              \
        P##1 = MFMA16(areg, wgt[wi][1], bsp[1]);                              \
        P##2 = MFMA16(areg, wgt[wi][2], bsp[2]);                              \
        P##3 = MFMA16(areg, wgt[wi][3], bsp[3]);                              \
    }
#define MM_RACC(P, areg, wi)                                                  \
    {                                                                         \
        P##0 = MFMA16(areg, wgt[wi][0], P##0);                                \
        P##1 = MFMA16(areg, wgt[wi][1], P##1);                                \
        P##2 = MFMA16(areg, wgt[wi][2], P##2);                                \
        P##3 = MFMA16(areg, wgt[wi][3], P##3);                                \
    }
#define MM_F(P, aptr, wi)                                                     \
    {                                                                         \
        f16x8 af = *(const f16x8*)(aptr);                                     \
        P##0 = MFMA16(af, wgt[wi][0], bsp[0]);                                \
        P##1 = MFMA16(af, wgt[wi][1], bsp[1]);                                \
        P##2 = MFMA16(af, wgt[wi][2], bsp[2]);                                \
        P##3 = MFMA16(af, wgt[wi][3], bsp[3]);                                \
    }
#define MM(P, aptr, wi)                                                       \
    {                                                                         \
        f16x8 af = *(const f16x8*)(aptr);                                     \
        P##0 = MFMA16(af, wgt[wi][0], P##0);                                  \
        P##1 = MFMA16(af, wgt[wi][1], P##1);                                  \
        P##2 = MFMA16(af, wgt[wi][2], P##2);                                  \
        P##3 = MFMA16(af, wgt[wi][3], P##3);                                  \
    }

// Breadth-first merged-rcp cell: all 4 rows advance in lockstep so the 4
// dependency chains interleave (issue-bound, not latency-bound).
//   sigmoid(f)=pig*R, i*g=(Eg-1)*ef1*R, R=rcp(pig*ef1);
//   o*tanh(c)=(Ec-1)*rcp((1+Eo)(1+Ec)). 5 exp2 + 2 rcp per output.
// C/D layout (m89): lane -> col(hid)=m16, rows(batch)=quad*4+r.
#define CELL(P, lh, PP)                                                       \
    {                                                                         \
        f16* hw = HBASE(PP, lh) + hid_self;                                   \
        float Ei[4], Ef[4], Eg[4], Eo[4], ef1[4], pig[4], R[4];               \
        float cn[4], Ec[4], Eo1[4], hv[4];                                    \
        _Pragma("unroll")                                                     \
        for (int r = 0; r < 4; ++r) Ei[r] = __builtin_amdgcn_exp2f(P##0[r]);  \
        _Pragma("unroll")                                                     \
        for (int r = 0; r < 4; ++r) Ef[r] = __builtin_amdgcn_exp2f(P##1[r]);  \
        _Pragma("unroll")                                                     \
        for (int r = 0; r < 4; ++r) Eg[r] = __builtin_amdgcn_exp2f(P##2[r]);  \
        _Pragma("unroll")                                                     \
        for (int r = 0; r < 4; ++r) Eo[r] = __builtin_amdgcn_exp2f(P##3[r]);  \
        _Pragma("unroll")                                                     \
        for (int r = 0; r < 4; ++r) {                                         \
            ef1[r] = 1.f + Ef[r];                                             \
            pig[r] = (1.f + Ei[r]) * (1.f + Eg[r]);                           \
            Eo1[r] = 1.f + Eo[r];                                             \
        }                                                                     \
        _Pragma("unroll")                                                     \
        for (int r = 0; r < 4; ++r)                                           \
            R[r] = __builtin_amdgcn_rcpf(pig[r] * ef1[r]);                    \
        _Pragma("unroll")                                                     \
        for (int r = 0; r < 4; ++r) {                                         \
            float fv = pig[r] * R[r];                                         \
            float ig = (Eg[r] - 1.f) * ef1[r] * R[r];                         \
            cn[r] = fmaf(fv, cst[r], ig);                                     \
            cst[r] = cn[r];                                                   \
        }                                                                     \
        _Pragma("unroll")                                                     \
        for (int r = 0; r < 4; ++r)                                           \
            Ec[r] = __builtin_amdgcn_exp2f(cn[r] * SCL_G);                    \
        _Pragma("unroll")                                                     \
        for (int r = 0; r < 4; ++r)                                           \
            hv[r] = __builtin_amdgcn_rcpf(Eo1[r] * (1.f + Ec[r]));            \
        _Pragma("unroll")                                                     \
        for (int r = 0; r < 4; ++r)                                           \
            hw[(quad * 4 + r) * HSTR] = (f16)((Ec[r] - 1.f) * hv[r]);         \
    }

    // ---------------- encoder (layer-pipelined, 1 RBAR/round) ----------------
    const float* xp = enc_x + (size_t)(bg + m16) * (TE * 8);
    f32x4 xa = {}, xb = {};
    f16x8 af_cur = {};
    if (role == 0) {
        xa = *(const f32x4*)xp; xb = *(const f32x4*)(xp + 4);
#pragma unroll
        for (int j = 0; j < 4; ++j) { af_cur[j] = (f16)xa[j]; af_cur[4 + j] = (f16)xb[j]; }
    }

// One pipelined round, parity PP. role0: L0(T0); role1: L1(T0-1);
// role2: L2(T0-2). All reads parity 1-PP, writes PP. setprio(1) covers the
// ds_read+MFMA section; CELL runs at prio 0 so sibling waves' MFMAs preempt.
#define ROUND(PP, D0, D1, D2, T0)                                             \
    {                                                                         \
        RBAR;                                                                 \
        f32x4 a0, a1, a2, a3;                                                 \
        if (role == 0) {                                                      \
            if (D0) {                                                         \
                PRIO_UP;                                                      \
                MM_R(a, af_cur, 0);                                           \
                const f16* h0p = HBASE(1 - (PP), 0) + aoff;                   \
                MM(a, h0p, 1);                                                \
                MM(a, h0p + 32, 2);                                           \
                PRIO_DN;                                                      \
                if ((T0) + 1 < TE) {                                          \
                    xa = *(const f32x4*)(xp + (size_t)((T0) + 1) * 8);        \
                    xb = *(const f32x4*)(xp + (size_t)((T0) + 1) * 8 + 4);    \
                }                                                             \
                CELL(a, 0, PP);                                               \
                if ((T0) + 1 < TE) {                                          \
                    _Pragma("unroll")                                         \
                    for (int j = 0; j < 4; ++j) {                             \
                        af_cur[j] = (f16)xa[j]; af_cur[4 + j] = (f16)xb[j];   \
                    }                                                         \
                }                                                             \
            }                                                                 \
        } else if (role == 1) {                                               \
            if (D1) {                                                         \
                PRIO_UP;                                                      \
                const f16* h0p = HBASE(1 - (PP), 0) + aoff;                   \
                const f16* h1p = HBASE(1 - (PP), 1) + aoff;                   \
                MM_F(a, h0p, 0);                                              \
                MM(a, h0p + 32, 1);                                           \
                MM(a, h1p, 2);                                                \
                MM(a, h1p + 32, 3);                                           \
                PRIO_DN;                                                      \
                CELL(a, 1, PP);                                               \
            }                                                                 \
        } else {                                                              \
            if (D2) {                                                         \
                PRIO_UP;                                                      \
                const f16* h1p = HBASE(1 - (PP), 1) + aoff;                   \
                const f16* h2p = HBASE(1 - (PP), 2) + aoff;                   \
                MM_F(a, h1p, 0);                                              \
                MM(a, h1p + 32, 1);                                           \
                MM(a, h2p, 2);                                                \
                MM(a, h2p + 32, 3);                                           \
                PRIO_DN;                                                      \
                CELL(a, 2, PP);                                               \
            }                                                                 \
        }                                                                     \
    }

    ROUND(0, 1, 0, 0, 0)                 // r=0:   L0(0)
    ROUND(1, 1, 1, 0, 1)                 // r=1:   L0(1), L1(0)
    for (int t = 2; t < 166; t += 2) {   // r=2..165 dense
        ROUND(0, 1, 1, 1, t)
        ROUND(1, 1, 1, 1, t + 1)
    }
    ROUND(0, 1, 1, 1, 166)
    ROUND(1, 1, 1, 1, 167)               // r=167: last L0
    ROUND(0, 0, 1, 1, 168)               // r=168: L1(167), L2(166)
    ROUND(1, 0, 0, 1, 169)               // r=169: L2(167)
    // exit parities: h0(167)->buf1, h1(167)->buf0, h2(167)->buf1

    // ---------------- decoder (serial; z feedback; 3 RBAR/step) ----------------
    // role0 per-lane state for batch m16 (redundant across quads & waves).
    float vf = 0.f, rvf = 0.f, bmv = 0.f, bav = 0.f, zn = 0.f, ep_hold = 0.f;
    float dxr[7] = {};
    f32x4 wmv4[4] = {}, wav4[4] = {};   // w_m/w_a for hid quad*16..+16
    if (role == 0) {
        vf  = v[bg + m16];
        rvf = 1.0f / vf;
        bmv = b_m[0]; bav = b_a[0];
        zn  = enc_z[(size_t)(bg + m16) * TE + (TE - 1)] * rvf;
        ep_hold = eps[(size_t)(bg + m16) * TD + 0];
#pragma unroll
        for (int j = 0; j < 7; ++j)
            dxr[j] = dec_x[((size_t)(bg + m16) * TD + 0) * 7 + j];
#pragma unroll
        for (int i = 0; i < 4; ++i) {
            wmv4[i] = *(const f32x4*)(w_m + quad * 16 + 4 * i);
            wav4[i] = *(const f32x4*)(w_a + quad * 16 + 4 * i);
        }
    }

// In-wave redundant head for time tOut (h2 in parity ppRead): lane = batch
// m16, hid chunk quad*16..+16; shfl_xor(16,32) sums the 4 quads. Uses
// ep_hold (= eps[tOut], prefetched). All role0 lanes end with zn.
#define HEAD(tOut, ppRead)                                                    \
    {                                                                         \
        const f16* h2p = HBASE(ppRead, 2) + m16 * HSTR + quad * 16;           \
        f16x8 ha = *(const f16x8*)h2p;                                        \
        f16x8 hc = *(const f16x8*)(h2p + 8);                                  \
        float sm = 0.f, sa = 0.f;                                             \
        _Pragma("unroll")                                                     \
        for (int i = 0; i < 4; ++i) {                                         \
            _Pragma("unroll")                                                 \
            for (int j = 0; j < 4; ++j) {                                     \
                float hv = (i < 2) ? (float)ha[i * 4 + j]                     \
                                   : (float)hc[(i - 2) * 4 + j];              \
                sm = fmaf(hv, wmv4[i][j], sm);                                \
                sa = fmaf(hv, wav4[i][j], sa);                                \
            }                                                                 \
        }                                                                     \
        sm += __shfl_xor(sm, 16, 64); sm += __shfl_xor(sm, 32, 64);           \
        sa += __shfl_xor(sa, 16, 64); sa += __shfl_xor(sa, 32, 64);           \
        float mo = (sm + bmv) * vf;                                           \
        float ao = softplusf(sa + bav) * vf;                                  \
        float zs = fmaf(ao, ep_hold, mo);                                     \
        if (tid < 16) out[(size_t)(bg + m16) * TD + (tOut)] = zs;             \
        zn = zs * rvf;                                                        \
    }

    // Step t: PA = t&1. Phase A: role0 head(t-1) [h2 in 1-PA] + L0(t)
    // [reads h0[1-PA], writes h0[PA]]; role1/2 pre-read recurrent frags.
    // Phase B: role1 L1(t) [reads h0[PA], writes h1[1-PA]]. Phase C:
    // role2 L2(t) [reads h1[1-PA], writes h2[PA]]. t=0 matches encoder
    // exit parities; the RBAR at the top of phase A publishes phase C.
    f16x8 pr_a = {}, pr_b = {};          // role1/2 recurrent pre-reads
    for (int t = 0; t < TD; ++t) {
        const int PA = t & 1;
        RBAR;   // previous step's h2 (or encoder exit) visible
        {
            f32x4 a0, a1, a2, a3;
            if (role == 0) {
                if (t > 0) {
                    HEAD(t - 1, 1 - PA);
                    ep_hold = eps[(size_t)(bg + m16) * TD + t];
                }
                f16x8 af;
                af[0] = (f16)zn;
#pragma unroll
                for (int j = 0; j < 7; ++j) af[1 + j] = (f16)dxr[j];
                MM_R(a, af, 0);
                const f16* h0p = HBASE(1 - PA, 0) + aoff;
                MM(a, h0p, 1);
                MM(a, h0p + 32, 2);
                CELL(a, 0, PA);
                if (t + 1 < TD) {
#pragma unroll
                    for (int j = 0; j < 7; ++j)
                        dxr[j] = dec_x[((size_t)(bg + m16) * TD + (t + 1)) * 7 + j];
                }
            } else if (role == 1) {
                // pre-read recurrent h1(t-1) [parity PA], written phase B(t-1)
                const f16* h1p = HBASE(PA, 1) + aoff;
                pr_a = *(const f16x8*)h1p;
                pr_b = *(const f16x8*)(h1p + 32);
            } else {
                // pre-read recurrent h2(t-1) [parity 1-PA], written phase C(t-1)
                const f16* h2p = HBASE(1 - PA, 2) + aoff;
                pr_a = *(const f16x8*)h2p;
                pr_b = *(const f16x8*)(h2p + 32);
            }
        }
        RBAR;   // h0[PA] visible
        if (role == 1) {
            f32x4 a0, a1, a2, a3;
            const f16* h0p = HBASE(PA, 0) + aoff;
            MM_F(a, h0p, 0);
            MM(a, h0p + 32, 1);
            MM_RACC(a, pr_a, 2);
            MM_RACC(a, pr_b, 3);
            CELL(a, 1, 1 - PA);
        }
        RBAR;   // h1[1-PA] visible
        if (role == 2) {
            f32x4 a0, a1, a2, a3;
            const f16* h1p = HBASE(1 - PA, 1) + aoff;
            MM_F(a, h1p, 0);
            MM(a, h1p + 32, 1);
            MM_RACC(a, pr_a, 2);
            MM_RACC(a, pr_b, 3);
            CELL(a, 2, PA);
        }
    }
    RBAR;   // h2(TD-1) visible
    // final head: t-1 = TD-1, h2 parity (TD-1)&1 = 1; ep_hold = eps[TD-1]
    if (role == 0) { HEAD(TD - 1, 1); }

#undef RBAR
#undef PRIO_UP
#undef PRIO_DN
#undef HBASE
#undef MFMA16
#undef MM_R
#undef MM_RACC
#undef MM_F
#undef MM
#undef CELL
#undef ROUND
#undef HEAD
}

extern "C" void kernel_launch(void* const* d_in, const int* in_sizes, int n_in,
                              void* d_out, int out_size, void* d_ws, size_t ws_size,
                              hipStream_t stream) {
    const float* enc_x = (const float*)d_in[0];
    const float* enc_z = (const float*)d_in[1];
    const float* dec_x = (const float*)d_in[2];
    const float* v     = (const float*)d_in[3];
    const float* eps   = (const float*)d_in[4];
    const float* Wih0  = (const float*)d_in[5];
    const float* Whh0  = (const float*)d_in[6];
    const float* b0    = (const float*)d_in[7];
    const float* Wih1  = (const float*)d_in[8];
    const float* Whh1  = (const float*)d_in[9];
    const float* b1    = (const float*)d_in[10];
    const float* Wih2  = (const float*)d_in[11];
    const float* Whh2  = (const float*)d_in[12];
    const float* b2    = (const float*)d_in[13];
    const float* w_m   = (const float*)d_in[14];
    const float* b_m   = (const float*)d_in[15];
    const float* w_a   = (const float*)d_in[16];
    const float* b_a   = (const float*)d_in[17];
    float* out = (float*)d_out;
    f16*   pk  = (f16*)d_ws;

    pack_kernel<<<384, 256, 0, stream>>>(Wih0, Whh0, Wih1, Whh1, Wih2, Whh2, pk);
    lstm_kernel<<<NWG, 768, 0, stream>>>(enc_x, enc_z, dec_x, v, eps, pk,
                                         b0, b1, b2, w_m, b_m, w_a, b_a, out);
}

// Round 9
// 296.465 us; speedup vs baseline: 1.0883x; 1.0883x over previous
//
#include <hip/hip_runtime.h>
#include <math.h>

#define B_TOT 4096
#define TE 168
#define TD 24
#define NWG 256          // 16 batches per WG; 768 threads -> 3 waves/SIMD
#define HSTR 72          // padded f16 row stride (144 B, 16B-aligned)

typedef _Float16 f16;
typedef __attribute__((ext_vector_type(8))) _Float16 f16x8;
typedef __attribute__((ext_vector_type(4))) float f32x4;

// Activation pre-scaling folded into weights/biases:
//   i,f,o: w *= -log2(e)  -> E = exp2(y) = e^{-x}; sigmoid = 1/(1+E)
//   g:     w *= 2*log2(e) -> E = e^{2x};  tanh = (E-1)/(E+1)
#define SCL_S (-1.4426950408889634f)
#define SCL_G (2.885390081777927f)

// ---------------------------------------------------------------------------
// Pack weights into MFMA B-fragment order, f16, pre-scaled per gate:
//   pk[w][l][q][c][lane][j] = scale_q * Wcomb_l[q*64+w*16+(lane&15)][c*32+(lane>>4)*8+j]
//   l=0 (K=96):  k<8 -> Wih0; 8..31 -> 0; 32..95 -> Whh0[k-32]  (c=3 all zero)
//   l=1 (K=128): k<64 -> Wih1 (input h0); else Whh1[k-64] (recurrent h1)
//   l=2 (K=128): k<64 -> Wih2 (input h1); else Whh2[k-64] (recurrent h2)
// ---------------------------------------------------------------------------
__global__ __launch_bounds__(256) void pack_kernel(
    const float* __restrict__ Wih0, const float* __restrict__ Whh0,
    const float* __restrict__ Wih1, const float* __restrict__ Whh1,
    const float* __restrict__ Wih2, const float* __restrict__ Whh2,
    f16* __restrict__ pk)
{
    int idx = blockIdx.x * 256 + threadIdx.x;   // 0 .. 98303
    int j = idx & 7;
    int t = idx >> 3;
    int ln = t & 63; t >>= 6;
    int c  = t & 3;  t >>= 2;
    int q  = t & 3;  t >>= 2;
    int l  = t % 3;
    int w  = t / 3;
    int row = q * 64 + w * 16 + (ln & 15);
    int k   = c * 32 + ((ln >> 4) << 3) + j;
    float val = 0.f;
    if (l == 0) {
        if (k < 8)                 val = Wih0[row * 8 + k];
        else if (k >= 32 && k < 96) val = Whh0[row * 64 + (k - 32)];
    } else if (l == 1) {
        val = (k < 64) ? Wih1[row * 64 + k] : Whh1[row * 64 + (k - 64)];
    } else {
        val = (k < 64) ? Wih2[row * 64 + k] : Whh2[row * 64 + (k - 64)];
    }
    const float sc = (q == 2) ? SCL_G : SCL_S;
    pk[idx] = (f16)(val * sc);
}

// softplus via 2 HW trans ops (no libm log1pf):
//   softplus(x) = max(x,0) + ln2 * log2(1 + 2^(-|x|*log2e))
__device__ __forceinline__ float softplusf(float x) {
    float t = fabsf(x) * 1.4426950408889634f;
    float E = __builtin_amdgcn_exp2f(-t);
    float L = __builtin_amdgcn_logf(1.f + E);      // log2
    return fmaxf(x, 0.f) + 0.6931471805599453f * L;
}

// ---------------------------------------------------------------------------
// 256 WGs x 768 threads (12 waves); WG owns 16 batches (M=16 tile dense).
// One LAYER per wave role: role = tid>>8 -> 0:L0, 1:L1, 2:L2; within a role,
// wave wv owns hid block wv*16..+16. Encoder layer-pipelined: round r
// computes L0(r), L1(r-1), L2(r-2); ONE RBAR per round (R9/R10, proven).
//
// R16 = R13 champion restored VERBATIM (242 us steady). R14 (lag pipeline)
// and R15 (breadth-first CELL) both regressed via divergent-code scratch
// spill (WRITE_SIZE 2.7 -> 11.1 / 9.6 MB). Lessons locked:
//  - no register state written under divergent exec may live across RBAR
//  - no added live-range widening inside CELL (depth-first is already
//    interleaved by the scheduler)
//  - compiler VGPR cap = 256/launch_bounds_arg2; 12-wave WG + 64-VGPR
//    weights/wave pins us at 1 WG/CU (register file), so arg2=2 (cap 128)
//    is free headroom.
// ---------------------------------------------------------------------------
__global__ __launch_bounds__(768, 2) void lstm_kernel(
    const float* __restrict__ enc_x, const float* __restrict__ enc_z,
    const float* __restrict__ dec_x, const float* __restrict__ v,
    const float* __restrict__ eps,   const f16* __restrict__ pk,
    const float* __restrict__ b0, const float* __restrict__ b1,
    const float* __restrict__ b2,
    const float* __restrict__ w_m, const float* __restrict__ b_m,
    const float* __restrict__ w_a, const float* __restrict__ b_a,
    float* __restrict__ out)
{
    const int tid  = threadIdx.x;
    const int lane = tid & 63;
    const int wv   = (tid >> 6) & 3;    // hid block within role
    const int role = tid >> 8;          // 0:L0, 1:L1, 2:L2
    const int bg   = blockIdx.x * 16;
    const int m16  = lane & 15;
    const int quad = lane >> 4;

    __shared__ f16 hbuf[2][3][16][HSTR];   // [parity][layer][batch][hid]

    // ---- zero LDS ----
    {
        uint* hz = (uint*)&hbuf[0][0][0][0];
        const int HW = 2 * 3 * 16 * HSTR / 2;   // 3456 words
        for (int i = tid; i < HW; i += 768) hz[i] = 0u;
    }

    // ---- weight fragments: this wave's layer only; fully unrolled,
    //      compile-time indices -> register-resident. ----
    f16x8 wgt[4][4];                    // [chunk][gate]
#define PKOFF(l, q, c) ((((((size_t)wv * 3 + (l)) * 4 + (q)) * 4 + (c)) * 64 + lane) * 8)
    {
        const f16* pkr = pk + PKOFF(role, 0, 0);
#pragma unroll
        for (int q = 0; q < 4; ++q)
#pragma unroll
            for (int c = 0; c < 4; ++c)
                wgt[c][q] = *(const f16x8*)(pkr + (q * 4 + c) * 64 * 8);
    }
#undef PKOFF

    const int hid_self = wv * 16 + m16;
    // bias splats (pre-scaled) for this wave's layer; MFMA C operand
    f32x4 bsp[4];
    {
        const float* bp = (role == 0) ? b0 : (role == 1) ? b1 : b2;
#pragma unroll
        for (int q = 0; q < 4; ++q) {
            const float sc = (q == 2) ? SCL_G : SCL_S;
            float bv = bp[q * 64 + hid_self] * sc;
            bsp[q] = (f32x4){bv, bv, bv, bv};
        }
    }

    f16* hb = &hbuf[0][0][0][0];
    const int aoff = m16 * HSTR + quad * 8;
    float cst[4] = {};                  // cell state for this wave's layer

// Raw barrier: drain only LDS ops (lgkmcnt); leave global loads/stores in
// flight. Memory-clobber asm on both sides pins LDS ops against reordering
// across the barrier.
#define RBAR                                                                  \
    {                                                                         \
        asm volatile("s_waitcnt lgkmcnt(0)" ::: "memory");                    \
        __builtin_amdgcn_s_barrier();                                         \
        asm volatile("" ::: "memory");                                        \
    }

#define PRIO_UP __builtin_amdgcn_s_setprio(1)
#define PRIO_DN __builtin_amdgcn_s_setprio(0)

#define HBASE(pp, l) (hb + ((pp) * 3 + (l)) * (16 * HSTR))
#define MFMA16(af, bf, cf) __builtin_amdgcn_mfma_f32_16x16x32_f16(af, bf, cf, 0, 0, 0)

#define MM_R(P, areg, wi)                                                     \
    {                                                                         \
        P##0 = MFMA16(areg, wgt[wi][0], bsp[0]);                              \
        P##1 = MFMA16(areg, wgt[wi][1], bsp[1]);                              \
        P##2 = MFMA16(areg, wgt[wi][2], bsp[2]);                              \
        P##3 = MFMA16(areg, wgt[wi][3], bsp[3]);                              \
    }
#define MM_RACC(P, areg, wi)                                                  \
    {                                                                         \
        P##0 = MFMA16(areg, wgt[wi][0], P##0);                                \
        P##1 = MFMA16(areg, wgt[wi][1], P##1);                                \
        P##2 = MFMA16(areg, wgt[wi][2], P##2);                                \
        P##3 = MFMA16(areg, wgt[wi][3], P##3);                                \
    }
#define MM_F(P, aptr, wi)                                                     \
    {                                                                         \
        f16x8 af = *(const f16x8*)(aptr);                                     \
        P##0 = MFMA16(af, wgt[wi][0], bsp[0]);                                \
        P##1 = MFMA16(af, wgt[wi][1], bsp[1]);                                \
        P##2 = MFMA16(af, wgt[wi][2], bsp[2]);                                \
        P##3 = MFMA16(af, wgt[wi][3], bsp[3]);                                \
    }
#define MM(P, aptr, wi)                                                       \
    {                                                                         \
        f16x8 af = *(const f16x8*)(aptr);                                     \
        P##0 = MFMA16(af, wgt[wi][0], P##0);                                  \
        P##1 = MFMA16(af, wgt[wi][1], P##1);                                  \
        P##2 = MFMA16(af, wgt[wi][2], P##2);                                  \
        P##3 = MFMA16(af, wgt[wi][3], P##3);                                  \
    }

// Merged-rcp cell: sigmoid(f)=pig*R, i*g=(Eg-1)*ef1*R, R=rcp(pig*ef1);
// o*tanh(c)=(Ec-1)*rcp((1+Eo)(1+Ec)). 5 exp2 + 2 rcp per output.
// C/D layout (m89): lane -> col(hid)=m16, rows(batch)=quad*4+r.
#define CELL(P, lh, PP)                                                       \
    {                                                                         \
        f16* hw = HBASE(PP, lh) + hid_self;                                   \
        _Pragma("unroll")                                                     \
        for (int r = 0; r < 4; ++r) {                                         \
            float Ei = __builtin_amdgcn_exp2f(P##0[r]);                       \
            float Ef = __builtin_amdgcn_exp2f(P##1[r]);                       \
            float Eg = __builtin_amdgcn_exp2f(P##2[r]);                       \
            float Eo = __builtin_amdgcn_exp2f(P##3[r]);                       \
            float ef1 = 1.f + Ef;                                             \
            float pig = (1.f + Ei) * (1.f + Eg);                              \
            float R   = __builtin_amdgcn_rcpf(pig * ef1);                     \
            float fv  = pig * R;                                              \
            float ig  = (Eg - 1.f) * ef1 * R;                                 \
            float cn  = fmaf(fv, cst[r], ig);                                 \
            cst[r] = cn;                                                      \
            float Ec  = __builtin_amdgcn_exp2f(cn * SCL_G);                   \
            float Roc = __builtin_amdgcn_rcpf((1.f + Eo) * (1.f + Ec));       \
            hw[(quad * 4 + r) * HSTR] = (f16)((Ec - 1.f) * Roc);              \
        }                                                                     \
    }

    // ---------------- encoder (layer-pipelined, 1 RBAR/round) ----------------
    const float* xp = enc_x + (size_t)(bg + m16) * (TE * 8);
    f32x4 xa = {}, xb = {};
    f16x8 af_cur = {};
    if (role == 0) {
        xa = *(const f32x4*)xp; xb = *(const f32x4*)(xp + 4);
#pragma unroll
        for (int j = 0; j < 4; ++j) { af_cur[j] = (f16)xa[j]; af_cur[4 + j] = (f16)xb[j]; }
    }

// One pipelined round, parity PP. role0: L0(T0); role1: L1(T0-1);
// role2: L2(T0-2). All reads parity 1-PP, writes PP. setprio(1) covers the
// ds_read+MFMA section; CELL runs at prio 0 so sibling waves' MFMAs preempt.
#define ROUND(PP, D0, D1, D2, T0)                                             \
    {                                                                         \
        RBAR;                                                                 \
        f32x4 a0, a1, a2, a3;                                                 \
        if (role == 0) {                                                      \
            if (D0) {                                                         \
                PRIO_UP;                                                      \
                MM_R(a, af_cur, 0);                                           \
                const f16* h0p = HBASE(1 - (PP), 0) + aoff;                   \
                MM(a, h0p, 1);                                                \
                MM(a, h0p + 32, 2);                                           \
                PRIO_DN;                                                      \
                if ((T0) + 1 < TE) {                                          \
                    xa = *(const f32x4*)(xp + (size_t)((T0) + 1) * 8);        \
                    xb = *(const f32x4*)(xp + (size_t)((T0) + 1) * 8 + 4);    \
                }                                                             \
                CELL(a, 0, PP);                                               \
                if ((T0) + 1 < TE) {                                          \
                    _Pragma("unroll")                                         \
                    for (int j = 0; j < 4; ++j) {                             \
                        af_cur[j] = (f16)xa[j]; af_cur[4 + j] = (f16)xb[j];   \
                    }                                                         \
                }                                                             \
            }                                                                 \
        } else if (role == 1) {                                               \
            if (D1) {                                                         \
                PRIO_UP;                                                      \
                const f16* h0p = HBASE(1 - (PP), 0) + aoff;                   \
                const f16* h1p = HBASE(1 - (PP), 1) + aoff;                   \
                MM_F(a, h0p, 0);                                              \
                MM(a, h0p + 32, 1);                                           \
                MM(a, h1p, 2);                                                \
                MM(a, h1p + 32, 3);                                           \
                PRIO_DN;                                                      \
                CELL(a, 1, PP);                                               \
            }                                                                 \
        } else {                                                              \
            if (D2) {                                                         \
                PRIO_UP;                                                      \
                const f16* h1p = HBASE(1 - (PP), 1) + aoff;                   \
                const f16* h2p = HBASE(1 - (PP), 2) + aoff;                   \
                MM_F(a, h1p, 0);                                              \
                MM(a, h1p + 32, 1);                                           \
                MM(a, h2p, 2);                                                \
                MM(a, h2p + 32, 3);                                           \
                PRIO_DN;                                                      \
                CELL(a, 2, PP);                                               \
            }                                                                 \
        }                                                                     \
    }

    ROUND(0, 1, 0, 0, 0)                 // r=0:   L0(0)
    ROUND(1, 1, 1, 0, 1)                 // r=1:   L0(1), L1(0)
    for (int t = 2; t < 166; t += 2) {   // r=2..165 dense
        ROUND(0, 1, 1, 1, t)
        ROUND(1, 1, 1, 1, t + 1)
    }
    ROUND(0, 1, 1, 1, 166)
    ROUND(1, 1, 1, 1, 167)               // r=167: last L0
    ROUND(0, 0, 1, 1, 168)               // r=168: L1(167), L2(166)
    ROUND(1, 0, 0, 1, 169)               // r=169: L2(167)
    // exit parities: h0(167)->buf1, h1(167)->buf0, h2(167)->buf1

    // ---------------- decoder (serial; z feedback; 3 RBAR/step) ----------------
    // role0 per-lane state for batch m16 (redundant across quads & waves).
    float vf = 0.f, rvf = 0.f, bmv = 0.f, bav = 0.f, zn = 0.f, ep_hold = 0.f;
    float dxr[7] = {};
    f32x4 wmv4[4] = {}, wav4[4] = {};   // w_m/w_a for hid quad*16..+16
    if (role == 0) {
        vf  = v[bg + m16];
        rvf = 1.0f / vf;
        bmv = b_m[0]; bav = b_a[0];
        zn  = enc_z[(size_t)(bg + m16) * TE + (TE - 1)] * rvf;
        ep_hold = eps[(size_t)(bg + m16) * TD + 0];
#pragma unroll
        for (int j = 0; j < 7; ++j)
            dxr[j] = dec_x[((size_t)(bg + m16) * TD + 0) * 7 + j];
#pragma unroll
        for (int i = 0; i < 4; ++i) {
            wmv4[i] = *(const f32x4*)(w_m + quad * 16 + 4 * i);
            wav4[i] = *(const f32x4*)(w_a + quad * 16 + 4 * i);
        }
    }

// In-wave redundant head for time tOut (h2 in parity ppRead): lane = batch
// m16, hid chunk quad*16..+16; shfl_xor(16,32) sums the 4 quads. Uses
// ep_hold (= eps[tOut], prefetched). All role0 lanes end with zn.
#define HEAD(tOut, ppRead)                                                    \
    {                                                                         \
        const f16* h2p = HBASE(ppRead, 2) + m16 * HSTR + quad * 16;           \
        f16x8 ha = *(const f16x8*)h2p;                                        \
        f16x8 hc = *(const f16x8*)(h2p + 8);                                  \
        float sm = 0.f, sa = 0.f;                                             \
        _Pragma("unroll")                                                     \
        for (int i = 0; i < 4; ++i) {                                         \
            _Pragma("unroll")                                                 \
            for (int j = 0; j < 4; ++j) {                                     \
                float hv = (i < 2) ? (float)ha[i * 4 + j]                     \
                                   : (float)hc[(i - 2) * 4 + j];              \
                sm = fmaf(hv, wmv4[i][j], sm);                                \
                sa = fmaf(hv, wav4[i][j], sa);                                \
            }                                                                 \
        }                                                                     \
        sm += __shfl_xor(sm, 16, 64); sm += __shfl_xor(sm, 32, 64);           \
        sa += __shfl_xor(sa, 16, 64); sa += __shfl_xor(sa, 32, 64);           \
        float mo = (sm + bmv) * vf;                                           \
        float ao = softplusf(sa + bav) * vf;                                  \
        float zs = fmaf(ao, ep_hold, mo);                                     \
        if (tid < 16) out[(size_t)(bg + m16) * TD + (tOut)] = zs;             \
        zn = zs * rvf;                                                        \
    }

    // Step t: PA = t&1. Phase A: role0 head(t-1) [h2 in 1-PA] + L0(t)
    // [reads h0[1-PA], writes h0[PA]]; role1/2 pre-read recurrent frags.
    // Phase B: role1 L1(t) [reads h0[PA], writes h1[1-PA]]. Phase C:
    // role2 L2(t) [reads h1[1-PA], writes h2[PA]]. t=0 matches encoder
    // exit parities; the RBAR at the top of phase A publishes phase C.
    f16x8 pr_a = {}, pr_b = {};          // role1/2 recurrent pre-reads
    for (int t = 0; t < TD; ++t) {
        const int PA = t & 1;
        RBAR;   // previous step's h2 (or encoder exit) visible
        {
            f32x4 a0, a1, a2, a3;
            if (role == 0) {
                if (t > 0) {
                    HEAD(t - 1, 1 - PA);
                    ep_hold = eps[(size_t)(bg + m16) * TD + t];
                }
                f16x8 af;
                af[0] = (f16)zn;
#pragma unroll
                for (int j = 0; j < 7; ++j) af[1 + j] = (f16)dxr[j];
                MM_R(a, af, 0);
                const f16* h0p = HBASE(1 - PA, 0) + aoff;
                MM(a, h0p, 1);
                MM(a, h0p + 32, 2);
                CELL(a, 0, PA);
                if (t + 1 < TD) {
#pragma unroll
                    for (int j = 0; j < 7; ++j)
                        dxr[j] = dec_x[((size_t)(bg + m16) * TD + (t + 1)) * 7 + j];
                }
            } else if (role == 1) {
                // pre-read recurrent h1(t-1) [parity PA], written phase B(t-1)
                const f16* h1p = HBASE(PA, 1) + aoff;
                pr_a = *(const f16x8*)h1p;
                pr_b = *(const f16x8*)(h1p + 32);
            } else {
                // pre-read recurrent h2(t-1) [parity 1-PA], written phase C(t-1)
                const f16* h2p = HBASE(1 - PA, 2) + aoff;
                pr_a = *(const f16x8*)h2p;
                pr_b = *(const f16x8*)(h2p + 32);
            }
        }
        RBAR;   // h0[PA] visible
        if (role == 1) {
            f32x4 a0, a1, a2, a3;
            const f16* h0p = HBASE(PA, 0) + aoff;
            MM_F(a, h0p, 0);
            MM(a, h0p + 32, 1);
            MM_RACC(a, pr_a, 2);
            MM_RACC(a, pr_b, 3);
            CELL(a, 1, 1 - PA);
        }
        RBAR;   // h1[1-PA] visible
        if (role == 2) {
            f32x4 a0, a1, a2, a3;
            const f16* h1p = HBASE(1 - PA, 1) + aoff;
            MM_F(a, h1p, 0);
            MM(a, h1p + 32, 1);
            MM_RACC(a, pr_a, 2);
            MM_RACC(a, pr_b, 3);
            CELL(a, 2, PA);
        }
    }
    RBAR;   // h2(TD-1) visible
    // final head: t-1 = TD-1, h2 parity (TD-1)&1 = 1; ep_hold = eps[TD-1]
    if (role == 0) { HEAD(TD - 1, 1); }

#undef RBAR
#undef PRIO_UP
#undef PRIO_DN
#undef HBASE
#undef MFMA16
#undef MM_R
#undef MM_RACC
#undef MM_F
#undef MM
#undef CELL
#undef ROUND
#undef HEAD
}

extern "C" void kernel_launch(void* const* d_in, const int* in_sizes, int n_in,
                              void* d_out, int out_size, void* d_ws, size_t ws_size,
                              hipStream_t stream) {
    const float* enc_x = (const float*)d_in[0];
    const float* enc_z = (const float*)d_in[1];
    const float* dec_x = (const float*)d_in[2];
    const float* v     = (const float*)d_in[3];
    const float* eps   = (const float*)d_in[4];
    const float* Wih0  = (const float*)d_in[5];
    const float* Whh0  = (const float*)d_in[6];
    const float* b0    = (const float*)d_in[7];
    const float* Wih1  = (const float*)d_in[8];
    const float* Whh1  = (const float*)d_in[9];
    const float* b1    = (const float*)d_in[10];
    const float* Wih2  = (const float*)d_in[11];
    const float* Whh2  = (const float*)d_in[12];
    const float* b2    = (const float*)d_in[13];
    const float* w_m   = (const float*)d_in[14];
    const float* b_m   = (const float*)d_in[15];
    const float* w_a   = (const float*)d_in[16];
    const float* b_a   = (const float*)d_in[17];
    float* out = (float*)d_out;
    f16*   pk  = (f16*)d_ws;

    pack_kernel<<<384, 256, 0, stream>>>(Wih0, Whh0, Wih1, Whh1, Wih2, Whh2, pk);
    lstm_kernel<<<NWG, 768, 0, stream>>>(enc_x, enc_z, dec_x, v, eps, pk,
                                         b0, b1, b2, w_m, b_m, w_a, b_a, out);
}

// Round 12
// 296.033 us; speedup vs baseline: 1.0899x; 1.0015x over previous
//
#include <hip/hip_runtime.h>
#include <math.h>

#define B_TOT 4096
#define TE 168
#define TD 24
#define NWG 256          // 16 batches per WG; 768 threads -> 3 waves/SIMD
#define HSTR 72          // padded f16 row stride (144 B, 16B-aligned)

typedef _Float16 f16;
typedef __attribute__((ext_vector_type(8))) _Float16 f16x8;
typedef __attribute__((ext_vector_type(4))) float f32x4;

// Activation pre-scaling folded into weights/biases:
//   i,f,o: w *= -log2(e)  -> E = exp2(y) = e^{-x}; sigmoid = 1/(1+E)
//   g:     w *= 2*log2(e) -> E = e^{2x};  tanh = (E-1)/(E+1)
#define SCL_S (-1.4426950408889634f)
#define SCL_G (2.885390081777927f)

// ---------------------------------------------------------------------------
// Pack weights into MFMA B-fragment order, f16, pre-scaled per gate:
//   pk[w][l][q][c][lane][j] = scale_q * Wcomb_l[q*64+w*16+(lane&15)][c*32+(lane>>4)*8+j]
//   l=0 (K=96):  k<8 -> Wih0; 8..31 -> 0; 32..95 -> Whh0[k-32]  (c=3 all zero)
//   l=1 (K=128): k<64 -> Wih1 (input h0); else Whh1[k-64] (recurrent h1)
//   l=2 (K=128): k<64 -> Wih2 (input h1); else Whh2[k-64] (recurrent h2)
// ---------------------------------------------------------------------------
__global__ __launch_bounds__(256) void pack_kernel(
    const float* __restrict__ Wih0, const float* __restrict__ Whh0,
    const float* __restrict__ Wih1, const float* __restrict__ Whh1,
    const float* __restrict__ Wih2, const float* __restrict__ Whh2,
    f16* __restrict__ pk)
{
    int idx = blockIdx.x * 256 + threadIdx.x;   // 0 .. 98303
    int j = idx & 7;
    int t = idx >> 3;
    int ln = t & 63; t >>= 6;
    int c  = t & 3;  t >>= 2;
    int q  = t & 3;  t >>= 2;
    int l  = t % 3;
    int w  = t / 3;
    int row = q * 64 + w * 16 + (ln & 15);
    int k   = c * 32 + ((ln >> 4) << 3) + j;
    float val = 0.f;
    if (l == 0) {
        if (k < 8)                 val = Wih0[row * 8 + k];
        else if (k >= 32 && k < 96) val = Whh0[row * 64 + (k - 32)];
    } else if (l == 1) {
        val = (k < 64) ? Wih1[row * 64 + k] : Whh1[row * 64 + (k - 64)];
    } else {
        val = (k < 64) ? Wih2[row * 64 + k] : Whh2[row * 64 + (k - 64)];
    }
    const float sc = (q == 2) ? SCL_G : SCL_S;
    pk[idx] = (f16)(val * sc);
}

// softplus via 2 HW trans ops (no libm log1pf):
//   softplus(x) = max(x,0) + ln2 * log2(1 + 2^(-|x|*log2e))
__device__ __forceinline__ float softplusf(float x) {
    float t = fabsf(x) * 1.4426950408889634f;
    float E = __builtin_amdgcn_exp2f(-t);
    float L = __builtin_amdgcn_logf(1.f + E);      // log2
    return fmaxf(x, 0.f) + 0.6931471805599453f * L;
}

// ---------------------------------------------------------------------------
// 256 WGs x 768 threads (12 waves); WG owns 16 batches (M=16 tile dense).
// One LAYER per wave role: role = tid>>8 -> 0:L0, 1:L1, 2:L2; within a role,
// wave wv owns hid block wv*16..+16. Encoder layer-pipelined: round r
// computes L0(r), L1(r-1), L2(r-2); ONE RBAR per round.
//
// Champion (R13/R16) — resubmitted verbatim after R11-round infra failure.
// Locked lessons:
//  - MFMA A-fragments pin lane (m16,quad) -> A[m16][quad*8+j]: NO
//    row-dependent column swizzle of an LDS tile consumed as fragments.
//  - CELL ds_write_b16s are the 8M bank-conflict source (quads 0/2 & 1/3
//    collide; ~185 cy/round) — unfixable without rule-#20 dynamic indexing
//    or critical-path shuffles, both inside the +-3% noise band.
//  - no register state written under divergent exec may live across RBAR
//    (R11/R14/R15 all spilled; WRITE_SIZE is the canary).
//  - compiler VGPR cap = 256/launch_bounds_arg2; 1 WG/CU is register-file
//    pinned (64-VGPR weights x 12 waves), so arg2=2 (cap 128) is free.
// ---------------------------------------------------------------------------
__global__ __launch_bounds__(768, 2) void lstm_kernel(
    const float* __restrict__ enc_x, const float* __restrict__ enc_z,
    const float* __restrict__ dec_x, const float* __restrict__ v,
    const float* __restrict__ eps,   const f16* __restrict__ pk,
    const float* __restrict__ b0, const float* __restrict__ b1,
    const float* __restrict__ b2,
    const float* __restrict__ w_m, const float* __restrict__ b_m,
    const float* __restrict__ w_a, const float* __restrict__ b_a,
    float* __restrict__ out)
{
    const int tid  = threadIdx.x;
    const int lane = tid & 63;
    const int wv   = (tid >> 6) & 3;    // hid block within role
    const int role = tid >> 8;          // 0:L0, 1:L1, 2:L2
    const int bg   = blockIdx.x * 16;
    const int m16  = lane & 15;
    const int quad = lane >> 4;

    __shared__ f16 hbuf[2][3][16][HSTR];   // [parity][layer][batch][hid]

    // ---- zero LDS ----
    {
        uint* hz = (uint*)&hbuf[0][0][0][0];
        const int HW = 2 * 3 * 16 * HSTR / 2;   // 3456 words
        for (int i = tid; i < HW; i += 768) hz[i] = 0u;
    }

    // ---- weight fragments: this wave's layer only; fully unrolled,
    //      compile-time indices -> register-resident. ----
    f16x8 wgt[4][4];                    // [chunk][gate]
#define PKOFF(l, q, c) ((((((size_t)wv * 3 + (l)) * 4 + (q)) * 4 + (c)) * 64 + lane) * 8)
    {
        const f16* pkr = pk + PKOFF(role, 0, 0);
#pragma unroll
        for (int q = 0; q < 4; ++q)
#pragma unroll
            for (int c = 0; c < 4; ++c)
                wgt[c][q] = *(const f16x8*)(pkr + (q * 4 + c) * 64 * 8);
    }
#undef PKOFF

    const int hid_self = wv * 16 + m16;
    // bias splats (pre-scaled) for this wave's layer; MFMA C operand
    f32x4 bsp[4];
    {
        const float* bp = (role == 0) ? b0 : (role == 1) ? b1 : b2;
#pragma unroll
        for (int q = 0; q < 4; ++q) {
            const float sc = (q == 2) ? SCL_G : SCL_S;
            float bv = bp[q * 64 + hid_self] * sc;
            bsp[q] = (f32x4){bv, bv, bv, bv};
        }
    }

    f16* hb = &hbuf[0][0][0][0];
    const int aoff = m16 * HSTR + quad * 8;
    float cst[4] = {};                  // cell state for this wave's layer

// Raw barrier: drain only LDS ops (lgkmcnt); leave global loads/stores in
// flight. Memory-clobber asm on both sides pins LDS ops against reordering
// across the barrier.
#define RBAR                                                                  \
    {                                                                         \
        asm volatile("s_waitcnt lgkmcnt(0)" ::: "memory");                    \
        __builtin_amdgcn_s_barrier();                                         \
        asm volatile("" ::: "memory");                                        \
    }

#define PRIO_UP __builtin_amdgcn_s_setprio(1)
#define PRIO_DN __builtin_amdgcn_s_setprio(0)

#define HBASE(pp, l) (hb + ((pp) * 3 + (l)) * (16 * HSTR))
#define MFMA16(af, bf, cf) __builtin_amdgcn_mfma_f32_16x16x32_f16(af, bf, cf, 0, 0, 0)

#define MM_R(P, areg, wi)                                                     \
    {                                                                         \
        P##0 = MFMA16(areg, wgt[wi][0], bsp[0]);                              \
        P##1 = MFMA16(areg, wgt[wi][1], bsp[1]);                              \
        P##2 = MFMA16(areg, wgt[wi][2], bsp[2]);                              \
        P##3 = MFMA16(areg, wgt[wi][3], bsp[3]);                              \
    }
#define MM_RACC(P, areg, wi)                                                  \
    {                                                                         \
        P##0 = MFMA16(areg, wgt[wi][0], P##0);                                \
        P##1 = MFMA16(areg, wgt[wi][1], P##1);                                \
        P##2 = MFMA16(areg, wgt[wi][2], P##2);                                \
        P##3 = MFMA16(areg, wgt[wi][3], P##3);                                \
    }
#define MM_F(P, aptr, wi)                                                     \
    {                                                                         \
        f16x8 af = *(const f16x8*)(aptr);                                     \
        P##0 = MFMA16(af, wgt[wi][0], bsp[0]);                                \
        P##1 = MFMA16(af, wgt[wi][1], bsp[1]);                                \
        P##2 = MFMA16(af, wgt[wi][2], bsp[2]);                                \
        P##3 = MFMA16(af, wgt[wi][3], bsp[3]);                                \
    }
#define MM(P, aptr, wi)                                                       \
    {                                                                         \
        f16x8 af = *(const f16x8*)(aptr);                                     \
        P##0 = MFMA16(af, wgt[wi][0], P##0);                                  \
        P##1 = MFMA16(af, wgt[wi][1], P##1);                                  \
        P##2 = MFMA16(af, wgt[wi][2], P##2);                                  \
        P##3 = MFMA16(af, wgt[wi][3], P##3);                                  \
    }

// Merged-rcp cell: sigmoid(f)=pig*R, i*g=(Eg-1)*ef1*R, R=rcp(pig*ef1);
// o*tanh(c)=(Ec-1)*rcp((1+Eo)(1+Ec)). 5 exp2 + 2 rcp per output.
// C/D layout (m89): lane -> col(hid)=m16, rows(batch)=quad*4+r.
#define CELL(P, lh, PP)                                                       \
    {                                                                         \
        f16* hw = HBASE(PP, lh) + hid_self;                                   \
        _Pragma("unroll")                                                     \
        for (int r = 0; r < 4; ++r) {                                         \
            float Ei = __builtin_amdgcn_exp2f(P##0[r]);                       \
            float Ef = __builtin_amdgcn_exp2f(P##1[r]);                       \
            float Eg = __builtin_amdgcn_exp2f(P##2[r]);                       \
            float Eo = __builtin_amdgcn_exp2f(P##3[r]);                       \
            float ef1 = 1.f + Ef;                                             \
            float pig = (1.f + Ei) * (1.f + Eg);                              \
            float R   = __builtin_amdgcn_rcpf(pig * ef1);                     \
            float fv  = pig * R;                                              \
            float ig  = (Eg - 1.f) * ef1 * R;                                 \
            float cn  = fmaf(fv, cst[r], ig);                                 \
            cst[r] = cn;                                                      \
            float Ec  = __builtin_amdgcn_exp2f(cn * SCL_G);                   \
            float Roc = __builtin_amdgcn_rcpf((1.f + Eo) * (1.f + Ec));       \
            hw[(quad * 4 + r) * HSTR] = (f16)((Ec - 1.f) * Roc);              \
        }                                                                     \
    }

    // ---------------- encoder (layer-pipelined, 1 RBAR/round) ----------------
    const float* xp = enc_x + (size_t)(bg + m16) * (TE * 8);
    f32x4 xa = {}, xb = {};
    f16x8 af_cur = {};
    if (role == 0) {
        xa = *(const f32x4*)xp; xb = *(const f32x4*)(xp + 4);
#pragma unroll
        for (int j = 0; j < 4; ++j) { af_cur[j] = (f16)xa[j]; af_cur[4 + j] = (f16)xb[j]; }
    }

// One pipelined round, parity PP. role0: L0(T0); role1: L1(T0-1);
// role2: L2(T0-2). All reads parity 1-PP, writes PP. setprio(1) covers the
// ds_read+MFMA section; CELL runs at prio 0 so sibling waves' MFMAs preempt.
#define ROUND(PP, D0, D1, D2, T0)                                             \
    {                                                                         \
        RBAR;                                                                 \
        f32x4 a0, a1, a2, a3;                                                 \
        if (role == 0) {                                                      \
            if (D0) {                                                         \
                PRIO_UP;                                                      \
                MM_R(a, af_cur, 0);                                           \
                const f16* h0p = HBASE(1 - (PP), 0) + aoff;                   \
                MM(a, h0p, 1);                                                \
                MM(a, h0p + 32, 2);                                           \
                PRIO_DN;                                                      \
                if ((T0) + 1 < TE) {                                          \
                    xa = *(const f32x4*)(xp + (size_t)((T0) + 1) * 8);        \
                    xb = *(const f32x4*)(xp + (size_t)((T0) + 1) * 8 + 4);    \
                }                                                             \
                CELL(a, 0, PP);                                               \
                if ((T0) + 1 < TE) {                                          \
                    _Pragma("unroll")                                         \
                    for (int j = 0; j < 4; ++j) {                             \
                        af_cur[j] = (f16)xa[j]; af_cur[4 + j] = (f16)xb[j];   \
                    }                                                         \
                }                                                             \
            }                                                                 \
        } else if (role == 1) {                                               \
            if (D1) {                                                         \
                PRIO_UP;                                                      \
                const f16* h0p = HBASE(1 - (PP), 0) + aoff;                   \
                const f16* h1p = HBASE(1 - (PP), 1) + aoff;                   \
                MM_F(a, h0p, 0);                                              \
                MM(a, h0p + 32, 1);                                           \
                MM(a, h1p, 2);                                                \
                MM(a, h1p + 32, 3);                                           \
                PRIO_DN;                                                      \
                CELL(a, 1, PP);                                               \
            }                                                                 \
        } else {                                                              \
            if (D2) {                                                         \
                PRIO_UP;                                                      \
                const f16* h1p = HBASE(1 - (PP), 1) + aoff;                   \
                const f16* h2p = HBASE(1 - (PP), 2) + aoff;                   \
                MM_F(a, h1p, 0);                                              \
                MM(a, h1p + 32, 1);                                           \
                MM(a, h2p, 2);                                                \
                MM(a, h2p + 32, 3);                                           \
                PRIO_DN;                                                      \
                CELL(a, 2, PP);                                               \
            }                                                                 \
        }                                                                     \
    }

    ROUND(0, 1, 0, 0, 0)                 // r=0:   L0(0)
    ROUND(1, 1, 1, 0, 1)                 // r=1:   L0(1), L1(0)
    for (int t = 2; t < 166; t += 2) {   // r=2..165 dense
        ROUND(0, 1, 1, 1, t)
        ROUND(1, 1, 1, 1, t + 1)
    }
    ROUND(0, 1, 1, 1, 166)
    ROUND(1, 1, 1, 1, 167)               // r=167: last L0
    ROUND(0, 0, 1, 1, 168)               // r=168: L1(167), L2(166)
    ROUND(1, 0, 0, 1, 169)               // r=169: L2(167)
    // exit parities: h0(167)->buf1, h1(167)->buf0, h2(167)->buf1

    // ---------------- decoder (serial; z feedback; 3 RBAR/step) ----------------
    // role0 per-lane state for batch m16 (redundant across quads & waves).
    float vf = 0.f, rvf = 0.f, bmv = 0.f, bav = 0.f, zn = 0.f, ep_hold = 0.f;
    float dxr[7] = {};
    f32x4 wmv4[4] = {}, wav4[4] = {};   // w_m/w_a for hid quad*16..+16
    if (role == 0) {
        vf  = v[bg + m16];
        rvf = 1.0f / vf;
        bmv = b_m[0]; bav = b_a[0];
        zn  = enc_z[(size_t)(bg + m16) * TE + (TE - 1)] * rvf;
        ep_hold = eps[(size_t)(bg + m16) * TD + 0];
#pragma unroll
        for (int j = 0; j < 7; ++j)
            dxr[j] = dec_x[((size_t)(bg + m16) * TD + 0) * 7 + j];
#pragma unroll
        for (int i = 0; i < 4; ++i) {
            wmv4[i] = *(const f32x4*)(w_m + quad * 16 + 4 * i);
            wav4[i] = *(const f32x4*)(w_a + quad * 16 + 4 * i);
        }
    }

// In-wave redundant head for time tOut (h2 in parity ppRead): lane = batch
// m16, hid chunk quad*16..+16; shfl_xor(16,32) sums the 4 quads. Uses
// ep_hold (= eps[tOut], prefetched). All role0 lanes end with zn.
#define HEAD(tOut, ppRead)                                                    \
    {                                                                         \
        const f16* h2p = HBASE(ppRead, 2) + m16 * HSTR + quad * 16;           \
        f16x8 ha = *(const f16x8*)h2p;                                        \
        f16x8 hc = *(const f16x8*)(h2p + 8);                                  \
        float sm = 0.f, sa = 0.f;                                             \
        _Pragma("unroll")                                                     \
        for (int i = 0; i < 4; ++i) {                                         \
            _Pragma("unroll")                                                 \
            for (int j = 0; j < 4; ++j) {                                     \
                float hv = (i < 2) ? (float)ha[i * 4 + j]                     \
                                   : (float)hc[(i - 2) * 4 + j];              \
                sm = fmaf(hv, wmv4[i][j], sm);                                \
                sa = fmaf(hv, wav4[i][j], sa);                                \
            }                                                                 \
        }                                                                     \
        sm += __shfl_xor(sm, 16, 64); sm += __shfl_xor(sm, 32, 64);           \
        sa += __shfl_xor(sa, 16, 64); sa += __shfl_xor(sa, 32, 64);           \
        float mo = (sm + bmv) * vf;                                           \
        float ao = softplusf(sa + bav) * vf;                                  \
        float zs = fmaf(ao, ep_hold, mo);                                     \
        if (tid < 16) out[(size_t)(bg + m16) * TD + (tOut)] = zs;             \
        zn = zs * rvf;                                                        \
    }

    // Step t: PA = t&1. Phase A: role0 head(t-1) [h2 in 1-PA] + L0(t)
    // [reads h0[1-PA], writes h0[PA]]; role1/2 pre-read recurrent frags.
    // Phase B: role1 L1(t) [reads h0[PA], writes h1[1-PA]]. Phase C:
    // role2 L2(t) [reads h1[1-PA], writes h2[PA]]. t=0 matches encoder
    // exit parities; the RBAR at the top of phase A publishes phase C.
    f16x8 pr_a = {}, pr_b = {};          // role1/2 recurrent pre-reads
    for (int t = 0; t < TD; ++t) {
        const int PA = t & 1;
        RBAR;   // previous step's h2 (or encoder exit) visible
        {
            f32x4 a0, a1, a2, a3;
            if (role == 0) {
                if (t > 0) {
                    HEAD(t - 1, 1 - PA);
                    ep_hold = eps[(size_t)(bg + m16) * TD + t];
                }
                f16x8 af;
                af[0] = (f16)zn;
#pragma unroll
                for (int j = 0; j < 7; ++j) af[1 + j] = (f16)dxr[j];
                MM_R(a, af, 0);
                const f16* h0p = HBASE(1 - PA, 0) + aoff;
                MM(a, h0p, 1);
                MM(a, h0p + 32, 2);
                CELL(a, 0, PA);
                if (t + 1 < TD) {
#pragma unroll
                    for (int j = 0; j < 7; ++j)
                        dxr[j] = dec_x[((size_t)(bg + m16) * TD + (t + 1)) * 7 + j];
                }
            } else if (role == 1) {
                // pre-read recurrent h1(t-1) [parity PA], written phase B(t-1)
                const f16* h1p = HBASE(PA, 1) + aoff;
                pr_a = *(const f16x8*)h1p;
                pr_b = *(const f16x8*)(h1p + 32);
            } else {
                // pre-read recurrent h2(t-1) [parity 1-PA], written phase C(t-1)
                const f16* h2p = HBASE(1 - PA, 2) + aoff;
                pr_a = *(const f16x8*)h2p;
                pr_b = *(const f16x8*)(h2p + 32);
            }
        }
        RBAR;   // h0[PA] visible
        if (role == 1) {
            f32x4 a0, a1, a2, a3;
            const f16* h0p = HBASE(PA, 0) + aoff;
            MM_F(a, h0p, 0);
            MM(a, h0p + 32, 1);
            MM_RACC(a, pr_a, 2);
            MM_RACC(a, pr_b, 3);
            CELL(a, 1, 1 - PA);
        }
        RBAR;   // h1[1-PA] visible
        if (role == 2) {
            f32x4 a0, a1, a2, a3;
            const f16* h1p = HBASE(1 - PA, 1) + aoff;
            MM_F(a, h1p, 0);
            MM(a, h1p + 32, 1);
            MM_RACC(a, pr_a, 2);
            MM_RACC(a, pr_b, 3);
            CELL(a, 2, PA);
        }
    }
    RBAR;   // h2(TD-1) visible
    // final head: t-1 = TD-1, h2 parity (TD-1)&1 = 1; ep_hold = eps[TD-1]
    if (role == 0) { HEAD(TD - 1, 1); }

#undef RBAR
#undef PRIO_UP
#undef PRIO_DN
#undef HBASE
#undef MFMA16
#undef MM_R
#undef MM_RACC
#undef MM_F
#undef MM
#undef CELL
#undef ROUND
#undef HEAD
}

extern "C" void kernel_launch(void* const* d_in, const int* in_sizes, int n_in,
                              void* d_out, int out_size, void* d_ws, size_t ws_size,
                              hipStream_t stream) {
    const float* enc_x = (const float*)d_in[0];
    const float* enc_z = (const float*)d_in[1];
    const float* dec_x = (const float*)d_in[2];
    const float* v     = (const float*)d_in[3];
    const float* eps   = (const float*)d_in[4];
    const float* Wih0  = (const float*)d_in[5];
    const float* Whh0  = (const float*)d_in[6];
    const float* b0    = (const float*)d_in[7];
    const float* Wih1  = (const float*)d_in[8];
    const float* Whh1  = (const float*)d_in[9];
    const float* b1    = (const float*)d_in[10];
    const float* Wih2  = (const float*)d_in[11];
    const float* Whh2  = (const float*)d_in[12];
    const float* b2    = (const float*)d_in[13];
    const float* w_m   = (const float*)d_in[14];
    const float* b_m   = (const float*)d_in[15];
    const float* w_a   = (const float*)d_in[16];
    const float* b_a   = (const float*)d_in[17];
    float* out = (float*)d_out;
    f16*   pk  = (f16*)d_ws;

    pack_kernel<<<384, 256, 0, stream>>>(Wih0, Whh0, Wih1, Whh1, Wih2, Whh2, pk);
    lstm_kernel<<<NWG, 768, 0, stream>>>(enc_x, enc_z, dec_x, v, eps, pk,
                                         b0, b1, b2, w_m, b_m, w_a, b_a, out);
}